// Round 2
// baseline (487.739 us; speedup 1.0000x reference)
//
#include <hip/hip_runtime.h>

// ---------------- problem constants ----------------
#define B_SZ   256
#define NTOK   197
#define DLOC   512
#define DGLB   768
#define MFINE  (B_SZ*NTOK)    // 50432 = 394*128
#define TOPK   5

// output layout (float32, concatenated)
#define OUT_GFEAT 0
#define OUT_LSE   196608
#define OUT_FINE  196609
#define OUT_TOP   26017793

typedef ushort us8  __attribute__((ext_vector_type(8)));
typedef short  s16x8 __attribute__((ext_vector_type(8)));
typedef float  f32x4 __attribute__((ext_vector_type(4)));

__device__ __forceinline__ ushort f2bf(float x){
  unsigned u = __float_as_uint(x);
  unsigned r = u + 0x7fffu + ((u>>16)&1u);   // RNE
  return (ushort)(r>>16);
}
__device__ __forceinline__ float bf2f(ushort h){ return __uint_as_float(((unsigned)h)<<16); }

__device__ __forceinline__ void gl_lds16(const ushort* g, ushort* l){
  __builtin_amdgcn_global_load_lds((const __attribute__((address_space(1))) unsigned int*)g,
                                   (__attribute__((address_space(3))) unsigned int*)l, 16, 0, 0);
}

// ---------------- bf16 GEMM:  D[M,N] = f(A)[M,K] @ W[N,K]^T + bias ----------------
// AMODE 1: A is f32, convert to bf16 in staging
// AMODE 2: A is bf16 h, apply BN(scale/shift)+ReLU in staging; rows >= Mmain come
//          from Aext (pre-reduced mean rows, passthrough)
// EPI 0: write bf16 Hout + per-channel sum/sumsq atomics into stats
// EPI 1: write f32 Fout; EXT rows go to Tout row 6 (token average by linearity)
#define BM 128
#define BN 128
#define BK 64

template<int AMODE, int EPI, int EXT>
__global__ __launch_bounds__(256)
void k_gemm(const void* __restrict__ Asrc, const ushort* __restrict__ Aext,
            const ushort* __restrict__ W, const float* __restrict__ bias,
            const float* __restrict__ bnpar,
            ushort* __restrict__ Hout, float* __restrict__ Fout, float* __restrict__ Tout,
            float* __restrict__ stats, int Mmain, int N, int K, int ntn){
  __shared__ ushort As[BM*BK];
  __shared__ ushort Ws[BN*BK];
  const int tid = threadIdx.x;

  // bijective XCD-chunk swizzle (m204): consecutive logical blocks share an XCD L2
  const int nwg = gridDim.x;
  const int q = nwg >> 3, r = nwg & 7;
  const int x = blockIdx.x & 7, jj = blockIdx.x >> 3;
  const int lb = (x < r ? x*(q+1) : r*(q+1) + (x-r)*q) + jj;
  const int mt = lb / ntn, nt = lb % ntn;
  const int mBase = mt*BM, nBase = nt*BN;
  const int lane = tid & 63, wid = tid >> 6;
  const int wr = (wid>>1)*64, wc = (wid&1)*64;
  const int l15 = lane & 15, lg = lane >> 4;

  f32x4 acc[4][4];
  #pragma unroll
  for (int i=0;i<4;i++)
    #pragma unroll
    for (int j=0;j<4;j++){ acc[i][j][0]=0.f; acc[i][j][1]=0.f; acc[i][j][2]=0.f; acc[i][j][3]=0.f; }

  for (int kt=0; kt<K; kt+=BK){
    __syncthreads();
    // ---- A stage (reg-staged, fused transform, XOR-swizzled LDS write) ----
    #pragma unroll
    for (int p=0;p<4;p++){
      int c = p*256 + tid;
      int row = c >> 3, d = c & 7;          // d = 16B slot within row
      int grow = mBase + row;
      us8 v;
      if (AMODE == 1){
        const float* ap = (const float*)Asrc + (size_t)grow*K + kt + d*8;
        float4 f0 = *(const float4*)ap;
        float4 f1 = *(const float4*)(ap+4);
        v[0]=f2bf(f0.x); v[1]=f2bf(f0.y); v[2]=f2bf(f0.z); v[3]=f2bf(f0.w);
        v[4]=f2bf(f1.x); v[5]=f2bf(f1.y); v[6]=f2bf(f1.z); v[7]=f2bf(f1.w);
      } else {
        int c0 = kt + d*8;
        if (!EXT || grow < Mmain){
          us8 hv = *(const us8*)((const ushort*)Asrc + (size_t)grow*K + c0);
          float4 sc0 = *(const float4*)&bnpar[c0];
          float4 sc1 = *(const float4*)&bnpar[c0+4];
          float4 sh0 = *(const float4*)&bnpar[K+c0];
          float4 sh1 = *(const float4*)&bnpar[K+c0+4];
          v[0]=f2bf(fmaxf(bf2f(hv[0])*sc0.x+sh0.x,0.f));
          v[1]=f2bf(fmaxf(bf2f(hv[1])*sc0.y+sh0.y,0.f));
          v[2]=f2bf(fmaxf(bf2f(hv[2])*sc0.z+sh0.z,0.f));
          v[3]=f2bf(fmaxf(bf2f(hv[3])*sc0.w+sh0.w,0.f));
          v[4]=f2bf(fmaxf(bf2f(hv[4])*sc1.x+sh1.x,0.f));
          v[5]=f2bf(fmaxf(bf2f(hv[5])*sc1.y+sh1.y,0.f));
          v[6]=f2bf(fmaxf(bf2f(hv[6])*sc1.z+sh1.z,0.f));
          v[7]=f2bf(fmaxf(bf2f(hv[7])*sc1.w+sh1.w,0.f));
        } else {
          v = *(const us8*)(Aext + (size_t)(grow - Mmain)*K + c0);
        }
      }
      *(us8*)((char*)As + row*128 + ((d ^ (row&7))*16)) = v;
    }
    // ---- B stage: global_load_lds, pre-swizzled global source (m173) ----
    #pragma unroll
    for (int qq=0; qq<4; qq++){
      int ch = wid*4 + qq;                  // 1KB chunk = 8 rows
      int row = ch*8 + (lane>>3);
      int d = lane & 7;
      int scol = (d ^ (row & 7)) * 8;
      gl_lds16(&W[(size_t)(nBase+row)*K + kt + scol], &Ws[ch*512]);
    }
    __syncthreads();
    // ---- compute ----
    #pragma unroll
    for (int kk=0; kk<2; kk++){
      s16x8 a[4], b[4];
      #pragma unroll
      for (int i=0;i<4;i++){
        int row = wr + i*16 + l15;
        int sl = (kk*4+lg) ^ (row & 7);
        a[i] = *(const s16x8*)((const char*)As + row*128 + sl*16);
      }
      #pragma unroll
      for (int i=0;i<4;i++){
        int row = wc + i*16 + l15;
        int sl = (kk*4+lg) ^ (row & 7);
        b[i] = *(const s16x8*)((const char*)Ws + row*128 + sl*16);
      }
      #pragma unroll
      for (int i=0;i<4;i++)
        #pragma unroll
        for (int j2=0;j2<4;j2++)
          acc[i][j2] = __builtin_amdgcn_mfma_f32_16x16x32_bf16(a[i], b[j2], acc[i][j2], 0,0,0);
    }
  }

  const int rowBase = mBase + wr;
  const int colBase = nBase + wc;
  #pragma unroll
  for (int nj=0; nj<4; nj++){
    int col = colBase + nj*16 + l15;
    float bb = bias[col];
    float s1=0.f, s2=0.f;
    #pragma unroll
    for (int mi=0; mi<4; mi++){
      #pragma unroll
      for (int j=0;j<4;j++){
        float v = acc[mi][nj][j] + bb;
        int row = rowBase + mi*16 + lg*4 + j;   // C/D: col=lane&15, row=(lane>>4)*4+reg
        if (EPI==0){
          Hout[(size_t)row*N + col] = f2bf(v);
          s1 += v; s2 += v*v;
        } else {
          if (!EXT || row < Mmain) Fout[(size_t)row*N + col] = v;
          else Tout[((size_t)(row-Mmain)*7 + 6)*DLOC + col] = v;
        }
      }
    }
    if (EPI==0){
      s1 += __shfl_xor(s1,16); s1 += __shfl_xor(s1,32);
      s2 += __shfl_xor(s2,16); s2 += __shfl_xor(s2,32);
      if (lg==0){ atomicAdd(&stats[col], s1); atomicAdd(&stats[N+col], s2); }
    }
  }
}

// ---------------- both BN finalizes in one launch ----------------
__global__ void k_bn_finalize2(const float* __restrict__ sf, const float* __restrict__ gf,
                               const float* __restrict__ bef, float* __restrict__ pf,
                               const float* __restrict__ sg, const float* __restrict__ gg,
                               const float* __restrict__ beg, float* __restrict__ pg){
  int c = blockIdx.x*blockDim.x + threadIdx.x;
  if (c < 512){
    float mean = sf[c]*(1.f/(float)MFINE);
    float var  = sf[512+c]*(1.f/(float)MFINE) - mean*mean;
    float sc = gf[c]*rsqrtf(var + 1e-5f);
    pf[c] = sc; pf[512+c] = bef[c] - mean*sc;
  } else if (c < 1280){
    int d = c - 512;
    float mean = sg[d]*(1.f/(float)B_SZ);
    float var  = sg[768+d]*(1.f/(float)B_SZ) - mean*mean;
    float sc = gg[d]*rsqrtf(var + 1e-5f);
    pg[d] = sc; pg[768+d] = beg[d] - mean*sc;
  }
}

// ---------------- mean over tokens of BN(h) -> bf16 [256,512] ----------------
__global__ __launch_bounds__(256)
void k_hmean(const ushort* __restrict__ h, const float* __restrict__ par,
             ushort* __restrict__ hm){
  __shared__ float red[4][512];
  int b = blockIdx.x;
  int lane = threadIdx.x & 63, w = threadIdx.x >> 6;
  int c0 = lane*8;
  float4 sca = *(const float4*)&par[c0],     scb = *(const float4*)&par[c0+4];
  float4 sha = *(const float4*)&par[512+c0], shb = *(const float4*)&par[512+c0+4];
  float a0=0,a1=0,a2=0,a3=0,a4=0,a5=0,a6=0,a7=0;
  const ushort* base = h + (size_t)b*NTOK*DLOC;
  for (int n=w; n<NTOK; n+=4){
    us8 v = *(const us8*)&base[(size_t)n*DLOC + c0];
    a0 += fmaxf(bf2f(v[0])*sca.x+sha.x, 0.f);
    a1 += fmaxf(bf2f(v[1])*sca.y+sha.y, 0.f);
    a2 += fmaxf(bf2f(v[2])*sca.z+sha.z, 0.f);
    a3 += fmaxf(bf2f(v[3])*sca.w+sha.w, 0.f);
    a4 += fmaxf(bf2f(v[4])*scb.x+shb.x, 0.f);
    a5 += fmaxf(bf2f(v[5])*scb.y+shb.y, 0.f);
    a6 += fmaxf(bf2f(v[6])*scb.z+shb.z, 0.f);
    a7 += fmaxf(bf2f(v[7])*scb.w+shb.w, 0.f);
  }
  red[w][c0+0]=a0; red[w][c0+1]=a1; red[w][c0+2]=a2; red[w][c0+3]=a3;
  red[w][c0+4]=a4; red[w][c0+5]=a5; red[w][c0+6]=a6; red[w][c0+7]=a7;
  __syncthreads();
  int c = threadIdx.x;
  float s = red[0][c]+red[1][c]+red[2][c]+red[3][c];
  hm[(size_t)b*DLOC + c] = f2bf(s*(1.f/197.f));
  c += 256;
  s = red[0][c]+red[1][c]+red[2][c]+red[3][c];
  hm[(size_t)b*DLOC + c] = f2bf(s*(1.f/197.f));
}

// ---------------- weight converts, one launch ----------------
__global__ void k_wconv(const float* __restrict__ w0,const float* __restrict__ w1,
                        const float* __restrict__ w2,const float* __restrict__ w3,
                        ushort* __restrict__ o0, ushort* __restrict__ o1,
                        ushort* __restrict__ o2, ushort* __restrict__ o3){
  int i = blockIdx.x*blockDim.x + threadIdx.x;
  int st = gridDim.x*blockDim.x;
  for (; i < 188416; i += st){          // units of 8 floats
    const float* src; ushort* dst; int k;
    if (i < 32768){ src=w0; dst=o0; k=i; }
    else if (i < 65536){ src=w1; dst=o1; k=i-32768; }
    else if (i < 114688){ src=w2; dst=o2; k=i-65536; }
    else { src=w3; dst=o3; k=i-114688; }
    float4 a = ((const float4*)src)[k*2];
    float4 b = ((const float4*)src)[k*2+1];
    us8 o;
    o[0]=f2bf(a.x); o[1]=f2bf(a.y); o[2]=f2bf(a.z); o[3]=f2bf(a.w);
    o[4]=f2bf(b.x); o[5]=f2bf(b.y); o[6]=f2bf(b.z); o[7]=f2bf(b.w);
    ((us8*)dst)[k] = o;
  }
}

// ---------------- row L2 normalize (global feature) ----------------
__global__ __launch_bounds__(256)
void k_l2norm(const float* __restrict__ gbuf, float* __restrict__ outg){
  int b = blockIdx.x, t = threadIdx.x;
  float v0 = gbuf[(size_t)b*DGLB + t];
  float v1 = gbuf[(size_t)b*DGLB + 256 + t];
  float v2 = gbuf[(size_t)b*DGLB + 512 + t];
  float s = v0*v0 + v1*v1 + v2*v2;
  s += __shfl_xor(s, 1);  s += __shfl_xor(s, 2);  s += __shfl_xor(s, 4);
  s += __shfl_xor(s, 8);  s += __shfl_xor(s, 16); s += __shfl_xor(s, 32);
  __shared__ float red[4];
  if ((t&63)==0) red[t>>6] = s;
  __syncthreads();
  float r = rsqrtf(red[0]+red[1]+red[2]+red[3]);
  outg[(size_t)b*DGLB + t]       = v0*r;
  outg[(size_t)b*DGLB + 256 + t] = v1*r;
  outg[(size_t)b*DGLB + 512 + t] = v2*r;
}

__global__ void k_scalar_exp(const float* __restrict__ ls, float* __restrict__ o){
  if (blockIdx.x==0 && threadIdx.x==0) o[0] = expf(ls[0]);
}

// ---------------- top-k indices (descending, ties -> lower index) ----------------
__global__ void k_topk(const float* __restrict__ attn, int* __restrict__ idx){
  int b = blockIdx.x*blockDim.x + threadIdx.x;
  if (b >= B_SZ) return;
  const float* a = attn + (size_t)b*(NTOK-1);
  int ch[TOPK];
  #pragma unroll
  for (int j=0;j<TOPK;j++){
    float best = -3.4e38f; int bi = 0;
    for (int i=0;i<NTOK-1;i++){
      bool used = false;
      #pragma unroll
      for (int q2=0;q2<TOPK;q2++) used |= (q2<j && ch[q2]==i);
      float v = a[i];
      if (!used && v>best){ best=v; bi=i; }
    }
    ch[j]=bi;
  }
  idx[b*8+0] = 0;
  #pragma unroll
  for (int j=0;j<TOPK;j++) idx[b*8+1+j] = ch[j]+1;
}

// ---------------- gather top rows 0..5 ----------------
__global__ __launch_bounds__(128)
void k_gather(const float* __restrict__ X, const int* __restrict__ idx, float* __restrict__ T){
  int g = blockIdx.x;           // 0..B*6-1
  int b = g/6, j = g%6;
  int src = idx[b*8+j];
  const float* s = X + ((size_t)b*NTOK + src)*DLOC;
  float* d = T + ((size_t)b*7 + j)*DLOC;
  for (int t=threadIdx.x; t<DLOC; t+=128) d[t] = s[t];
}

// ---------------- launch ----------------
extern "C" void kernel_launch(void* const* d_in, const int* in_sizes, int n_in,
                              void* d_out, int out_size, void* d_ws, size_t ws_size,
                              hipStream_t stream){
  const float* image_features = (const float*)d_in[0];
  const float* fine_feat      = (const float*)d_in[1];
  const float* fine_attn      = (const float*)d_in[2];
  const float* logit_scale    = (const float*)d_in[3];
  const float* vpt_w1  = (const float*)d_in[4];
  const float* vpt_b1  = (const float*)d_in[5];
  const float* vpt_g1  = (const float*)d_in[6];
  const float* vpt_be1 = (const float*)d_in[7];
  const float* vpt_w2  = (const float*)d_in[8];
  const float* vpt_b2  = (const float*)d_in[9];
  const float* mid_w1  = (const float*)d_in[10];
  const float* mid_b1  = (const float*)d_in[11];
  const float* mid_g1  = (const float*)d_in[12];
  const float* mid_be1 = (const float*)d_in[13];
  const float* mid_w2  = (const float*)d_in[14];
  const float* mid_b2  = (const float*)d_in[15];

  float* out = (float*)d_out;
  char* ws = (char*)d_ws;
  size_t off = 0;
  auto alloc = [&](size_t bytes)->void*{
    void* p = ws + off; off += (bytes + 255) & ~(size_t)255; return p;
  };
  ushort* h_bf   = (ushort*)alloc((size_t)MFINE*DLOC*2);
  ushort* wm1    = (ushort*)alloc(512*512*2);
  ushort* wm2    = (ushort*)alloc(512*512*2);
  ushort* wv1    = (ushort*)alloc(768*512*2);
  ushort* wv2    = (ushort*)alloc((size_t)768*768*2);
  ushort* h1g    = (ushort*)alloc(256*768*2);
  ushort* hnmean = (ushort*)alloc(256*512*2);
  float*  gbuf   = (float*)alloc(256*768*4);
  float*  stats_f= (float*)alloc(512*2*4);
  float*  stats_g= (float*)alloc(768*2*4);
  float*  par_f  = (float*)alloc(512*2*4);
  float*  par_g  = (float*)alloc(768*2*4);
  int*    idx    = (int*)alloc(256*8*4);

  hipMemsetAsync(stats_f, 0, 512*2*4, stream);
  hipMemsetAsync(stats_g, 0, 768*2*4, stream);

  // weights -> bf16 (one kernel)
  k_wconv<<<736,256,0,stream>>>(mid_w1, mid_w2, vpt_w1, vpt_w2, wm1, wm2, wv1, wv2);

  // GEMM1: h = bf16(A_f32) @ W1^T + b1, with channel stats
  k_gemm<1,0,0><<<(MFINE/BM)*(DLOC/BN),256,0,stream>>>(
      fine_feat, nullptr, wm1, mid_b1, nullptr, h_bf, nullptr, nullptr, stats_f,
      MFINE, DLOC, DLOC, DLOC/BN);
  k_gemm<1,0,0><<<(B_SZ/BM)*(DGLB/BN),256,0,stream>>>(
      image_features, nullptr, wv1, vpt_b1, nullptr, h1g, nullptr, nullptr, stats_g,
      B_SZ, DGLB, DLOC, DGLB/BN);

  // BN finalize (both branches)
  k_bn_finalize2<<<5,256,0,stream>>>(stats_f, mid_g1, mid_be1, par_f,
                                     stats_g, vpt_g1, vpt_be1, par_g);

  // mean over tokens of BN(h) for the avg rows
  k_hmean<<<B_SZ,256,0,stream>>>(h_bf, par_f, hnmean);

  // GEMM2 fine: BN+ReLU fused on A; 256 extra mean-rows -> Tout row 6
  float* Xout = out + OUT_FINE;
  float* Tout = out + OUT_TOP;
  k_gemm<2,1,1><<<((MFINE+256)/BM)*(DLOC/BN),256,0,stream>>>(
      h_bf, hnmean, wm2, mid_b2, par_f, nullptr, Xout, Tout, nullptr,
      MFINE, DLOC, DLOC, DLOC/BN);

  // GEMM2 global: BN+ReLU fused on A
  k_gemm<2,1,0><<<(B_SZ/BM)*(DGLB/BN),256,0,stream>>>(
      h1g, nullptr, wv2, vpt_b2, par_g, nullptr, gbuf, nullptr, nullptr,
      B_SZ, DGLB, DGLB, DGLB/BN);

  // epilogues
  k_l2norm<<<B_SZ,256,0,stream>>>(gbuf, out + OUT_GFEAT);
  k_scalar_exp<<<1,64,0,stream>>>(logit_scale, out + OUT_LSE);
  k_topk<<<4,64,0,stream>>>(fine_attn, idx);
  k_gather<<<B_SZ*6,128,0,stream>>>(Xout, idx, Tout);
}

// Round 3
// 374.482 us; speedup vs baseline: 1.3024x; 1.3024x over previous
//
#include <hip/hip_runtime.h>

// ---------------- problem constants ----------------
#define B_SZ   256
#define NTOK   197
#define DLOC   512
#define DGLB   768
#define MFINE  (B_SZ*NTOK)    // 50432 = 394*128
#define TOPK   5

// output layout (float32, concatenated)
#define OUT_GFEAT 0
#define OUT_LSE   196608
#define OUT_FINE  196609
#define OUT_TOP   26017793

#define BM 128
#define BN 128
#define BK 64

typedef ushort us8  __attribute__((ext_vector_type(8)));
typedef short  s16x8 __attribute__((ext_vector_type(8)));
typedef float  f32x4 __attribute__((ext_vector_type(4)));

__device__ __forceinline__ ushort f2bf(float x){            // RNE (epilogue-quality)
  unsigned u = __float_as_uint(x);
  unsigned r = u + 0x7fffu + ((u>>16)&1u);
  return (ushort)(r>>16);
}
__device__ __forceinline__ float bf2f(ushort h){ return __uint_as_float(((unsigned)h)<<16); }

// pack two f32 -> two bf16 (round-half-up; error <= ulp/2 like RNE, negligible bias)
__device__ __forceinline__ unsigned pkbf(float a, float b){
  unsigned ua = __float_as_uint(a), ub = __float_as_uint(b);
  return ((ua + 0x8000u) >> 16) | ((ub + 0x8000u) & 0xffff0000u);
}
// unpack bf16 pair, y = relu(x*sc+sh), repack
__device__ __forceinline__ unsigned bnpk(unsigned u, float sca, float scb, float sha, float shb){
  float x0 = __uint_as_float(u << 16);
  float x1 = __uint_as_float(u & 0xffff0000u);
  float y0 = fmaxf(fmaf(x0, sca, sha), 0.f);
  float y1 = fmaxf(fmaf(x1, scb, shb), 0.f);
  return ((__float_as_uint(y0) + 0x8000u) >> 16) | ((__float_as_uint(y1) + 0x8000u) & 0xffff0000u);
}

__device__ __forceinline__ void gl_lds16(const ushort* g, ushort* l){
  __builtin_amdgcn_global_load_lds((const __attribute__((address_space(1))) unsigned int*)g,
                                   (__attribute__((address_space(3))) unsigned int*)l, 16, 0, 0);
}

// ============ 2-phase double-buffered bf16 GEMM, two problems per grid ============
// D[M,N] = f(A)[M,K] @ W[N,K]^T + bias
// AMODE 1: A f32 -> bf16 in staging.  AMODE 2: A bf16, BN(scale,shift)+ReLU in staging;
//          blocks with mBase>=Mmain read pre-reduced rows from Aext (passthrough).
// EPI 0: write bf16 H + per-channel sum/sumsq atomics to S.
// EPI 1: write f32 F (ext blocks -> T row 6, token average by linearity).
template<int AMODE, int EPI>
__global__ __launch_bounds__(256)
void k_gemm2ph(const void* __restrict__ A0, const ushort* __restrict__ Aext0,
               const ushort* __restrict__ W0, const float* __restrict__ bias0,
               const float* __restrict__ par0,
               ushort* __restrict__ H0, float* __restrict__ F0, float* __restrict__ T0,
               float* __restrict__ S0,
               int N0, int K0, int ntn0, int Mmain0, int nblk0,
               const void* __restrict__ A1, const ushort* __restrict__ W1,
               const float* __restrict__ bias1, const float* __restrict__ par1,
               ushort* __restrict__ H1, float* __restrict__ F1, float* __restrict__ S1,
               int N1, int K1, int ntn1){
  __shared__ ushort As[2*BM*BK];
  __shared__ ushort Ws[2*BN*BK];
  const int tid = threadIdx.x;

  // bijective XCD-chunk swizzle (m204)
  const int nwg = gridDim.x;
  const int q = nwg >> 3, r = nwg & 7;
  const int x = blockIdx.x & 7, jj = blockIdx.x >> 3;
  const int lb = (x < r ? x*(q+1) : r*(q+1) + (x-r)*q) + jj;

  const void* Asrc; const ushort* Aext; const ushort* W; const float* bias;
  const float* par; ushort* H; float* F; float* T; float* S;
  int N, K, ntn, Mmain, lb2;
  if (lb < nblk0){
    Asrc=A0; Aext=Aext0; W=W0; bias=bias0; par=par0; H=H0; F=F0; T=T0; S=S0;
    N=N0; K=K0; ntn=ntn0; Mmain=Mmain0; lb2=lb;
  } else {
    Asrc=A1; Aext=nullptr; W=W1; bias=bias1; par=par1; H=H1; F=F1; T=nullptr; S=S1;
    N=N1; K=K1; ntn=ntn1; Mmain=0x40000000; lb2=lb-nblk0;
  }
  const int mt = lb2 / ntn, nt = lb2 % ntn;
  const int mBase = mt*BM, nBase = nt*BN;
  const bool extblk = (AMODE==2) && (mBase >= Mmain);
  const int lane = tid & 63, wid = tid >> 6;
  const int wr = (wid>>1)*64, wc = (wid&1)*64;
  const int l15 = lane & 15, lg = lane >> 4;
  const int r0 = tid >> 3, d8 = (tid & 7)*8;

  f32x4 acc[4][4];
  #pragma unroll
  for (int i=0;i<4;i++)
    #pragma unroll
    for (int j=0;j<4;j++){ acc[i][j][0]=0.f; acc[i][j][1]=0.f; acc[i][j][2]=0.f; acc[i][j][3]=0.f; }

  float4 fa[4][2]; uint4 ha[4]; float4 pa, pb, pc, pd;

  auto issueA = [&](int kt){
    if (AMODE==1){
      const float* Af = (const float*)Asrc;
      #pragma unroll
      for (int p=0;p<4;p++){
        const float* ap = Af + (size_t)(mBase + p*32 + r0)*K + kt + d8;
        fa[p][0] = *(const float4*)ap;
        fa[p][1] = *(const float4*)(ap+4);
      }
    } else {
      pa = *(const float4*)&par[kt+d8];
      pb = *(const float4*)&par[kt+d8+4];
      pc = *(const float4*)&par[K+kt+d8];
      pd = *(const float4*)&par[K+kt+d8+4];
      const ushort* Ab = extblk ? (Aext + (size_t)(mBase - Mmain)*K)
                                : ((const ushort*)Asrc + (size_t)mBase*K);
      #pragma unroll
      for (int p=0;p<4;p++)
        ha[p] = *(const uint4*)(Ab + (size_t)(p*32 + r0)*K + kt + d8);
    }
  };
  auto writeA = [&](int buf){
    #pragma unroll
    for (int p=0;p<4;p++){
      int row = p*32 + r0;
      uint4 v;
      if (AMODE==1){
        v.x = pkbf(fa[p][0].x, fa[p][0].y); v.y = pkbf(fa[p][0].z, fa[p][0].w);
        v.z = pkbf(fa[p][1].x, fa[p][1].y); v.w = pkbf(fa[p][1].z, fa[p][1].w);
      } else if (!extblk){
        v.x = bnpk(ha[p].x, pa.x, pa.y, pc.x, pc.y);
        v.y = bnpk(ha[p].y, pa.z, pa.w, pc.z, pc.w);
        v.z = bnpk(ha[p].z, pb.x, pb.y, pd.x, pd.y);
        v.w = bnpk(ha[p].w, pb.z, pb.w, pd.z, pd.w);
      } else { v.x=ha[p].x; v.y=ha[p].y; v.z=ha[p].z; v.w=ha[p].w; }
      *(uint4*)((char*)As + buf*16384 + row*128 + (((tid&7) ^ (row&7))*16)) = v;
    }
  };
  auto stageB = [&](int kt, int buf){
    #pragma unroll
    for (int qq=0; qq<4; qq++){
      int ch = wid*4 + qq;                  // 1KB chunk = 8 rows
      int row = ch*8 + (lane>>3);
      int scol = ((lane&7) ^ (row & 7)) * 8;
      gl_lds16(&W[(size_t)(nBase+row)*K + kt + scol], &Ws[buf*8192 + ch*512]);
    }
  };

  // prologue: tile 0
  issueA(0);
  stageB(0, 0);
  writeA(0);
  __syncthreads();

  const int nsteps = K / BK;
  for (int t=0; t<nsteps; ++t){
    const int cur = t & 1;
    const bool pf = (t+1 < nsteps);
    if (pf){ issueA((t+1)*BK); stageB((t+1)*BK, cur^1); }
    #pragma unroll
    for (int kk=0; kk<2; kk++){
      s16x8 a[4], b[4];
      #pragma unroll
      for (int i=0;i<4;i++){
        int row = wr + i*16 + l15;
        int sl = (kk*4+lg) ^ (row & 7);
        a[i] = *(const s16x8*)((const char*)As + cur*16384 + row*128 + sl*16);
      }
      #pragma unroll
      for (int i=0;i<4;i++){
        int row = wc + i*16 + l15;
        int sl = (kk*4+lg) ^ (row & 7);
        b[i] = *(const s16x8*)((const char*)Ws + cur*16384 + row*128 + sl*16);
      }
      #pragma unroll
      for (int i=0;i<4;i++)
        #pragma unroll
        for (int j2=0;j2<4;j2++)
          acc[i][j2] = __builtin_amdgcn_mfma_f32_16x16x32_bf16(a[i], b[j2], acc[i][j2], 0,0,0);
    }
    if (pf) writeA(cur^1);
    __syncthreads();
  }

  // ---- epilogue (nj innermost -> contiguous line segments back-to-back) ----
  const int rowBase = mBase + wr;
  const int colBase = nBase + wc;
  float bb[4];
  #pragma unroll
  for (int nj=0;nj<4;nj++) bb[nj] = bias[colBase + nj*16 + l15];

  if (EPI==0){
    float s1[4]={0.f,0.f,0.f,0.f}, s2[4]={0.f,0.f,0.f,0.f};
    #pragma unroll
    for (int mi=0; mi<4; mi++)
      #pragma unroll
      for (int j=0;j<4;j++){
        size_t rb = (size_t)(rowBase + mi*16 + lg*4 + j)*N + colBase + l15;
        #pragma unroll
        for (int nj=0;nj<4;nj++){
          float v = acc[mi][nj][j] + bb[nj];
          H[rb + nj*16] = f2bf(v);
          s1[nj] += v; s2[nj] += v*v;
        }
      }
    #pragma unroll
    for (int nj=0;nj<4;nj++){
      float x1 = s1[nj], x2 = s2[nj];
      x1 += __shfl_xor(x1,16); x1 += __shfl_xor(x1,32);
      x2 += __shfl_xor(x2,16); x2 += __shfl_xor(x2,32);
      if (lg==0){
        atomicAdd(&S[colBase + nj*16 + l15],     x1);
        atomicAdd(&S[N + colBase + nj*16 + l15], x2);
      }
    }
  } else {
    if (!extblk){
      #pragma unroll
      for (int mi=0; mi<4; mi++)
        #pragma unroll
        for (int j=0;j<4;j++){
          size_t rb = (size_t)(rowBase + mi*16 + lg*4 + j)*N + colBase + l15;
          #pragma unroll
          for (int nj=0;nj<4;nj++)
            F[rb + nj*16] = acc[mi][nj][j] + bb[nj];
        }
    } else {
      #pragma unroll
      for (int mi=0; mi<4; mi++)
        #pragma unroll
        for (int j=0;j<4;j++){
          size_t rx = (size_t)(rowBase + mi*16 + lg*4 + j - Mmain)*7 + 6;
          #pragma unroll
          for (int nj=0;nj<4;nj++)
            T[rx*DLOC + colBase + nj*16 + l15] = acc[mi][nj][j] + bb[nj];
        }
    }
  }
}

// ---------------- both BN finalizes ----------------
__global__ void k_bn_finalize2(const float* __restrict__ sf, const float* __restrict__ gf,
                               const float* __restrict__ bef, float* __restrict__ pf,
                               const float* __restrict__ sg, const float* __restrict__ gg,
                               const float* __restrict__ beg, float* __restrict__ pg){
  int c = blockIdx.x*blockDim.x + threadIdx.x;
  if (c < 512){
    float mean = sf[c]*(1.f/(float)MFINE);
    float var  = sf[512+c]*(1.f/(float)MFINE) - mean*mean;
    float sc = gf[c]*rsqrtf(var + 1e-5f);
    pf[c] = sc; pf[512+c] = bef[c] - mean*sc;
  } else if (c < 1280){
    int d = c - 512;
    float mean = sg[d]*(1.f/(float)B_SZ);
    float var  = sg[768+d]*(1.f/(float)B_SZ) - mean*mean;
    float sc = gg[d]*rsqrtf(var + 1e-5f);
    pg[d] = sc; pg[768+d] = beg[d] - mean*sc;
  }
}

// ---------------- mean over tokens of BN(h) -> bf16 [256,512] ----------------
__global__ __launch_bounds__(256)
void k_hmean(const ushort* __restrict__ h, const float* __restrict__ par,
             ushort* __restrict__ hm){
  __shared__ float red[4][512];
  int b = blockIdx.x;
  int lane = threadIdx.x & 63, w = threadIdx.x >> 6;
  int c0 = lane*8;
  float4 sca = *(const float4*)&par[c0],     scb = *(const float4*)&par[c0+4];
  float4 sha = *(const float4*)&par[512+c0], shb = *(const float4*)&par[512+c0+4];
  float a0=0,a1=0,a2=0,a3=0,a4=0,a5=0,a6=0,a7=0;
  const ushort* base = h + (size_t)b*NTOK*DLOC;
  for (int n=w; n<NTOK; n+=4){
    us8 v = *(const us8*)&base[(size_t)n*DLOC + c0];
    a0 += fmaxf(bf2f(v[0])*sca.x+sha.x, 0.f);
    a1 += fmaxf(bf2f(v[1])*sca.y+sha.y, 0.f);
    a2 += fmaxf(bf2f(v[2])*sca.z+sha.z, 0.f);
    a3 += fmaxf(bf2f(v[3])*sca.w+sha.w, 0.f);
    a4 += fmaxf(bf2f(v[4])*scb.x+shb.x, 0.f);
    a5 += fmaxf(bf2f(v[5])*scb.y+shb.y, 0.f);
    a6 += fmaxf(bf2f(v[6])*scb.z+shb.z, 0.f);
    a7 += fmaxf(bf2f(v[7])*scb.w+shb.w, 0.f);
  }
  red[w][c0+0]=a0; red[w][c0+1]=a1; red[w][c0+2]=a2; red[w][c0+3]=a3;
  red[w][c0+4]=a4; red[w][c0+5]=a5; red[w][c0+6]=a6; red[w][c0+7]=a7;
  __syncthreads();
  int c = threadIdx.x;
  float s = red[0][c]+red[1][c]+red[2][c]+red[3][c];
  hm[(size_t)b*DLOC + c] = f2bf(s*(1.f/197.f));
  c += 256;
  s = red[0][c]+red[1][c]+red[2][c]+red[3][c];
  hm[(size_t)b*DLOC + c] = f2bf(s*(1.f/197.f));
}

// ---------------- weight converts + stats zero, one launch ----------------
__global__ void k_wconv(const float* __restrict__ w0,const float* __restrict__ w1,
                        const float* __restrict__ w2,const float* __restrict__ w3,
                        ushort* __restrict__ o0, ushort* __restrict__ o1,
                        ushort* __restrict__ o2, ushort* __restrict__ o3,
                        float* __restrict__ stats){
  int i = blockIdx.x*blockDim.x + threadIdx.x;
  if (i < 640){ float4 z = {0.f,0.f,0.f,0.f}; ((float4*)stats)[i] = z; }
  if (i < 188416){
    const float* src; ushort* dst; int k;
    if (i < 32768){ src=w0; dst=o0; k=i; }
    else if (i < 65536){ src=w1; dst=o1; k=i-32768; }
    else if (i < 114688){ src=w2; dst=o2; k=i-65536; }
    else { src=w3; dst=o3; k=i-114688; }
    float4 a = ((const float4*)src)[k*2];
    float4 b = ((const float4*)src)[k*2+1];
    us8 o;
    o[0]=f2bf(a.x); o[1]=f2bf(a.y); o[2]=f2bf(a.z); o[3]=f2bf(a.w);
    o[4]=f2bf(b.x); o[5]=f2bf(b.y); o[6]=f2bf(b.z); o[7]=f2bf(b.w);
    ((us8*)dst)[k] = o;
  }
}

// ---------------- row L2 normalize + logit_scale exp ----------------
__global__ __launch_bounds__(256)
void k_l2norm(const float* __restrict__ gbuf, float* __restrict__ outg,
              const float* __restrict__ ls, float* __restrict__ lse){
  int b = blockIdx.x, t = threadIdx.x;
  if (b==0 && t==0) lse[0] = expf(ls[0]);
  float v0 = gbuf[(size_t)b*DGLB + t];
  float v1 = gbuf[(size_t)b*DGLB + 256 + t];
  float v2 = gbuf[(size_t)b*DGLB + 512 + t];
  float s = v0*v0 + v1*v1 + v2*v2;
  s += __shfl_xor(s, 1);  s += __shfl_xor(s, 2);  s += __shfl_xor(s, 4);
  s += __shfl_xor(s, 8);  s += __shfl_xor(s, 16); s += __shfl_xor(s, 32);
  __shared__ float red[4];
  if ((t&63)==0) red[t>>6] = s;
  __syncthreads();
  float r = rsqrtf(red[0]+red[1]+red[2]+red[3]);
  outg[(size_t)b*DGLB + t]       = v0*r;
  outg[(size_t)b*DGLB + 256 + t] = v1*r;
  outg[(size_t)b*DGLB + 512 + t] = v2*r;
}

// ---------------- wave-parallel top-k + gather (one block per batch row) ----------------
__global__ __launch_bounds__(64)
void k_topk_gather(const float* __restrict__ attn, const float* __restrict__ X,
                   float* __restrict__ T){
  int b = blockIdx.x, lane = threadIdx.x;
  const float* a = attn + (size_t)b*(NTOK-1);
  float v[4];
  v[0]=a[lane]; v[1]=a[lane+64]; v[2]=a[lane+128];
  v[3] = (lane<4) ? a[lane+192] : -3.4e38f;
  int sel[6]; sel[0]=0;
  #pragma unroll
  for (int rr=0; rr<TOPK; rr++){
    float bv = v[0]; int bi = lane;
    if (v[1]>bv){bv=v[1]; bi=lane+64;}
    if (v[2]>bv){bv=v[2]; bi=lane+128;}
    if (v[3]>bv){bv=v[3]; bi=lane+192;}
    #pragma unroll
    for (int s=1;s<64;s<<=1){
      float ov = __shfl_xor(bv, s);
      int oi = __shfl_xor(bi, s);
      if (ov>bv || (ov==bv && oi<bi)){ bv=ov; bi=oi; }
    }
    sel[rr+1] = bi+1;
    if ((bi&63)==lane && (bi>>6) < 4) v[bi>>6] = -3.4e38f;
  }
  #pragma unroll
  for (int j=0;j<6;j++){
    const float* s = X + ((size_t)b*NTOK + sel[j])*DLOC;
    float* d = T + ((size_t)b*7 + j)*DLOC;
    #pragma unroll
    for (int t=0;t<8;t++) d[lane + t*64] = s[lane + t*64];
  }
}

// ---------------- launch ----------------
extern "C" void kernel_launch(void* const* d_in, const int* in_sizes, int n_in,
                              void* d_out, int out_size, void* d_ws, size_t ws_size,
                              hipStream_t stream){
  const float* image_features = (const float*)d_in[0];
  const float* fine_feat      = (const float*)d_in[1];
  const float* fine_attn      = (const float*)d_in[2];
  const float* logit_scale    = (const float*)d_in[3];
  const float* vpt_w1  = (const float*)d_in[4];
  const float* vpt_b1  = (const float*)d_in[5];
  const float* vpt_g1  = (const float*)d_in[6];
  const float* vpt_be1 = (const float*)d_in[7];
  const float* vpt_w2  = (const float*)d_in[8];
  const float* vpt_b2  = (const float*)d_in[9];
  const float* mid_w1  = (const float*)d_in[10];
  const float* mid_b1  = (const float*)d_in[11];
  const float* mid_g1  = (const float*)d_in[12];
  const float* mid_be1 = (const float*)d_in[13];
  const float* mid_w2  = (const float*)d_in[14];
  const float* mid_b2  = (const float*)d_in[15];

  float* out = (float*)d_out;
  char* ws = (char*)d_ws;
  size_t off = 0;
  auto alloc = [&](size_t bytes)->void*{
    void* p = ws + off; off += (bytes + 255) & ~(size_t)255; return p;
  };
  ushort* h_bf   = (ushort*)alloc((size_t)MFINE*DLOC*2);
  ushort* wm1    = (ushort*)alloc(512*512*2);
  ushort* wm2    = (ushort*)alloc(512*512*2);
  ushort* wv1    = (ushort*)alloc(768*512*2);
  ushort* wv2    = (ushort*)alloc((size_t)768*768*2);
  ushort* h1g    = (ushort*)alloc(256*768*2);
  ushort* hnmean = (ushort*)alloc(256*512*2);
  float*  gbuf   = (float*)alloc(256*768*4);
  float*  stats  = (float*)alloc(2560*4);          // [0..1023] fine, [1024..2559] global
  float*  par_f  = (float*)alloc(512*2*4);
  float*  par_g  = (float*)alloc(768*2*4);
  float*  stats_f = stats;
  float*  stats_g = stats + 1024;

  // weights -> bf16 + zero stats
  k_wconv<<<736,256,0,stream>>>(mid_w1, mid_w2, vpt_w1, vpt_w2, wm1, wm2, wv1, wv2, stats);

  // GEMM1 (fine + global merged): h = bf16(A_f32) @ W1^T + b1, channel stats
  {
    int nblk0 = (MFINE/BM)*(DLOC/BN);     // 1576
    int nblk1 = (B_SZ/BM)*(DGLB/BN);      // 12
    k_gemm2ph<1,0><<<nblk0+nblk1,256,0,stream>>>(
      fine_feat, nullptr, wm1, mid_b1, nullptr, h_bf, nullptr, nullptr, stats_f,
      DLOC, DLOC, DLOC/BN, MFINE, nblk0,
      image_features, wv1, vpt_b1, nullptr, h1g, nullptr, stats_g,
      DGLB, DLOC, DGLB/BN);
  }

  // BN finalize (both)
  k_bn_finalize2<<<5,256,0,stream>>>(stats_f, mid_g1, mid_be1, par_f,
                                     stats_g, vpt_g1, vpt_be1, par_g);

  // token-mean of BN(h) for the avg rows
  k_hmean<<<B_SZ,256,0,stream>>>(h_bf, par_f, hnmean);

  // GEMM2 (fine+ext + global merged): BN+ReLU fused on A
  float* Xout = out + OUT_FINE;
  float* Tout = out + OUT_TOP;
  {
    int nblk0 = ((MFINE+256)/BM)*(DLOC/BN);  // 1584
    int nblk1 = (B_SZ/BM)*(DGLB/BN);         // 12
    k_gemm2ph<2,1><<<nblk0+nblk1,256,0,stream>>>(
      h_bf, hnmean, wm2, mid_b2, par_f, nullptr, Xout, Tout, nullptr,
      DLOC, DLOC, DLOC/BN, MFINE, nblk0,
      h1g, wv2, vpt_b2, par_g, nullptr, gbuf, nullptr,
      DGLB, DGLB, DGLB/BN);
  }

  // epilogues
  k_l2norm<<<B_SZ,256,0,stream>>>(gbuf, out + OUT_GFEAT, logit_scale, out + OUT_LSE);
  k_topk_gather<<<B_SZ,64,0,stream>>>(fine_attn, Xout, Tout);
}

// Round 4
// 372.490 us; speedup vs baseline: 1.3094x; 1.0053x over previous
//
#include <hip/hip_runtime.h>

// ---------------- problem constants ----------------
#define B_SZ   256
#define NTOK   197
#define DLOC   512
#define DGLB   768
#define MFINE  (B_SZ*NTOK)    // 50432 = 394*128
#define TOPK   5

// output layout (float32, concatenated)
#define OUT_GFEAT 0
#define OUT_LSE   196608
#define OUT_FINE  196609
#define OUT_TOP   26017793

#define BM 128
#define BN 128
#define BK 64

typedef ushort us8  __attribute__((ext_vector_type(8)));
typedef short  s16x8 __attribute__((ext_vector_type(8)));
typedef float  f32x4 __attribute__((ext_vector_type(4)));

__device__ __forceinline__ ushort f2bf(float x){            // RNE (epilogue-quality)
  unsigned u = __float_as_uint(x);
  unsigned r = u + 0x7fffu + ((u>>16)&1u);
  return (ushort)(r>>16);
}
__device__ __forceinline__ float bf2f(ushort h){ return __uint_as_float(((unsigned)h)<<16); }

// pack two f32 -> two bf16 (round-half-up)
__device__ __forceinline__ unsigned pkbf(float a, float b){
  unsigned ua = __float_as_uint(a), ub = __float_as_uint(b);
  return ((ua + 0x8000u) >> 16) | ((ub + 0x8000u) & 0xffff0000u);
}
// unpack bf16 pair, y = relu(x*sc+sh), repack
__device__ __forceinline__ unsigned bnpk(unsigned u, float sca, float scb, float sha, float shb){
  float x0 = __uint_as_float(u << 16);
  float x1 = __uint_as_float(u & 0xffff0000u);
  float y0 = fmaxf(fmaf(x0, sca, sha), 0.f);
  float y1 = fmaxf(fmaf(x1, scb, shb), 0.f);
  return ((__float_as_uint(y0) + 0x8000u) >> 16) | ((__float_as_uint(y1) + 0x8000u) & 0xffff0000u);
}

__device__ __forceinline__ void gl_lds16(const ushort* g, ushort* l){
  __builtin_amdgcn_global_load_lds((const __attribute__((address_space(1))) unsigned int*)g,
                                   (__attribute__((address_space(3))) unsigned int*)l, 16, 0, 0);
}

// ============ 2-phase double-buffered bf16 GEMM, two problems per grid ============
// D[M,N] = f(A)[M,K] @ W[N,K]^T + bias
// AMODE 1: A f32 -> bf16 in staging.  AMODE 2: A bf16, BN(scale,shift)+ReLU in staging;
//          blocks with mBase>=Mmain read pre-reduced rows from Aext (passthrough).
// EPI 0: write bf16 H + per-channel sum/sumsq atomics to S.
// EPI 1: write f32 F (ext blocks -> T row 6, token average by linearity).
template<int AMODE, int EPI>
__global__ __launch_bounds__(256, 2)
void k_gemm2ph(const void* __restrict__ A0, const ushort* __restrict__ Aext0,
               const ushort* __restrict__ W0, const float* __restrict__ bias0,
               const float* __restrict__ par0,
               ushort* __restrict__ H0, float* __restrict__ F0, float* __restrict__ T0,
               float* __restrict__ S0,
               int N0, int K0, int ntn0, int Mmain0, int nblk0,
               const void* __restrict__ A1, const ushort* __restrict__ W1,
               const float* __restrict__ bias1, const float* __restrict__ par1,
               ushort* __restrict__ H1, float* __restrict__ F1, float* __restrict__ S1,
               int N1, int K1, int ntn1){
  __shared__ ushort As[2*BM*BK];
  __shared__ ushort Ws[2*BN*BK];
  const int tid = threadIdx.x;

  // bijective XCD-chunk swizzle (m204)
  const int nwg = gridDim.x;
  const int q = nwg >> 3, r = nwg & 7;
  const int x = blockIdx.x & 7, jj = blockIdx.x >> 3;
  const int lb = (x < r ? x*(q+1) : r*(q+1) + (x-r)*q) + jj;

  const void* Asrc; const ushort* Aext; const ushort* W; const float* bias;
  const float* par; ushort* H; float* F; float* T; float* S;
  int N, K, ntn, Mmain, lb2;
  if (lb < nblk0){
    Asrc=A0; Aext=Aext0; W=W0; bias=bias0; par=par0; H=H0; F=F0; T=T0; S=S0;
    N=N0; K=K0; ntn=ntn0; Mmain=Mmain0; lb2=lb;
  } else {
    Asrc=A1; Aext=nullptr; W=W1; bias=bias1; par=par1; H=H1; F=F1; T=nullptr; S=S1;
    N=N1; K=K1; ntn=ntn1; Mmain=0x40000000; lb2=lb-nblk0;
  }
  const int mt = lb2 / ntn, nt = lb2 % ntn;
  const int mBase = mt*BM, nBase = nt*BN;
  const bool extblk = (AMODE==2) && (mBase >= Mmain);
  const int lane = tid & 63, wid = tid >> 6;
  const int wr = (wid>>1)*64, wc = (wid&1)*64;
  const int l15 = lane & 15, lg = lane >> 4;
  const int r0 = tid >> 3, d8 = (tid & 7)*8;

  f32x4 acc[4][4];
  #pragma unroll
  for (int i=0;i<4;i++)
    #pragma unroll
    for (int j=0;j<4;j++){ acc[i][j][0]=0.f; acc[i][j][1]=0.f; acc[i][j][2]=0.f; acc[i][j][3]=0.f; }

  float4 fa[4][2]; uint4 ha[4]; float4 pa, pb, pc, pd;

  auto issueA = [&](int kt){
    if (AMODE==1){
      const float* Af = (const float*)Asrc;
      #pragma unroll
      for (int p=0;p<4;p++){
        const float* ap = Af + (size_t)(mBase + p*32 + r0)*K + kt + d8;
        fa[p][0] = *(const float4*)ap;
        fa[p][1] = *(const float4*)(ap+4);
      }
    } else {
      pa = *(const float4*)&par[kt+d8];
      pb = *(const float4*)&par[kt+d8+4];
      pc = *(const float4*)&par[K+kt+d8];
      pd = *(const float4*)&par[K+kt+d8+4];
      const ushort* Ab = extblk ? (Aext + (size_t)(mBase - Mmain)*K)
                                : ((const ushort*)Asrc + (size_t)mBase*K);
      #pragma unroll
      for (int p=0;p<4;p++)
        ha[p] = *(const uint4*)(Ab + (size_t)(p*32 + r0)*K + kt + d8);
    }
  };
  auto writeA = [&](int buf){
    #pragma unroll
    for (int p=0;p<4;p++){
      int row = p*32 + r0;
      uint4 v;
      if (AMODE==1){
        v.x = pkbf(fa[p][0].x, fa[p][0].y); v.y = pkbf(fa[p][0].z, fa[p][0].w);
        v.z = pkbf(fa[p][1].x, fa[p][1].y); v.w = pkbf(fa[p][1].z, fa[p][1].w);
      } else if (!extblk){
        v.x = bnpk(ha[p].x, pa.x, pa.y, pc.x, pc.y);
        v.y = bnpk(ha[p].y, pa.z, pa.w, pc.z, pc.w);
        v.z = bnpk(ha[p].z, pb.x, pb.y, pd.x, pd.y);
        v.w = bnpk(ha[p].w, pb.z, pb.w, pd.z, pd.w);
      } else { v.x=ha[p].x; v.y=ha[p].y; v.z=ha[p].z; v.w=ha[p].w; }
      *(uint4*)((char*)As + buf*16384 + row*128 + (((tid&7) ^ (row&7))*16)) = v;
    }
  };
  auto stageB = [&](int kt, int buf){
    #pragma unroll
    for (int qq=0; qq<4; qq++){
      int ch = wid*4 + qq;                  // 1KB chunk = 8 rows
      int row = ch*8 + (lane>>3);
      int scol = ((lane&7) ^ (row & 7)) * 8;
      gl_lds16(&W[(size_t)(nBase+row)*K + kt + scol], &Ws[buf*8192 + ch*512]);
    }
  };

  // prologue: tile 0
  issueA(0);
  stageB(0, 0);
  writeA(0);
  __syncthreads();

  const int nsteps = K / BK;
  for (int t=0; t<nsteps; ++t){
    const int cur = t & 1;
    const bool pf = (t+1 < nsteps);
    if (pf){ issueA((t+1)*BK); stageB((t+1)*BK, cur^1); }
    // pin: prefetch loads issue BEFORE the compute cluster (anti-sink fence)
    __builtin_amdgcn_sched_barrier(0);
    #pragma unroll
    for (int kk=0; kk<2; kk++){
      s16x8 a[4], b[4];
      #pragma unroll
      for (int i=0;i<4;i++){
        int row = wr + i*16 + l15;
        int sl = (kk*4+lg) ^ (row & 7);
        a[i] = *(const s16x8*)((const char*)As + cur*16384 + row*128 + sl*16);
      }
      #pragma unroll
      for (int i=0;i<4;i++){
        int row = wc + i*16 + l15;
        int sl = (kk*4+lg) ^ (row & 7);
        b[i] = *(const s16x8*)((const char*)Ws + cur*16384 + row*128 + sl*16);
      }
      #pragma unroll
      for (int i=0;i<4;i++)
        #pragma unroll
        for (int j2=0;j2<4;j2++)
          acc[i][j2] = __builtin_amdgcn_mfma_f32_16x16x32_bf16(a[i], b[j2], acc[i][j2], 0,0,0);
    }
    // pin: MFMA cluster completes issue before the A ds_write (vmcnt wait lands here)
    __builtin_amdgcn_sched_barrier(0);
    if (pf) writeA(cur^1);
    __syncthreads();
  }

  // ---- epilogue (nj innermost -> contiguous line segments back-to-back) ----
  const int rowBase = mBase + wr;
  const int colBase = nBase + wc;
  float bb[4];
  #pragma unroll
  for (int nj=0;nj<4;nj++) bb[nj] = bias[colBase + nj*16 + l15];

  if (EPI==0){
    float s1[4]={0.f,0.f,0.f,0.f}, s2[4]={0.f,0.f,0.f,0.f};
    #pragma unroll
    for (int mi=0; mi<4; mi++)
      #pragma unroll
      for (int j=0;j<4;j++){
        size_t rb = (size_t)(rowBase + mi*16 + lg*4 + j)*N + colBase + l15;
        #pragma unroll
        for (int nj=0;nj<4;nj++){
          float v = acc[mi][nj][j] + bb[nj];
          H[rb + nj*16] = f2bf(v);
          s1[nj] += v; s2[nj] += v*v;
        }
      }
    #pragma unroll
    for (int nj=0;nj<4;nj++){
      float x1 = s1[nj], x2 = s2[nj];
      x1 += __shfl_xor(x1,16); x1 += __shfl_xor(x1,32);
      x2 += __shfl_xor(x2,16); x2 += __shfl_xor(x2,32);
      if (lg==0){
        atomicAdd(&S[colBase + nj*16 + l15],     x1);
        atomicAdd(&S[N + colBase + nj*16 + l15], x2);
      }
    }
  } else {
    if (!extblk){
      #pragma unroll
      for (int mi=0; mi<4; mi++)
        #pragma unroll
        for (int j=0;j<4;j++){
          size_t rb = (size_t)(rowBase + mi*16 + lg*4 + j)*N + colBase + l15;
          #pragma unroll
          for (int nj=0;nj<4;nj++)
            F[rb + nj*16] = acc[mi][nj][j] + bb[nj];
        }
    } else {
      #pragma unroll
      for (int mi=0; mi<4; mi++)
        #pragma unroll
        for (int j=0;j<4;j++){
          size_t rx = (size_t)(rowBase + mi*16 + lg*4 + j - Mmain)*7 + 6;
          #pragma unroll
          for (int nj=0;nj<4;nj++)
            T[rx*DLOC + colBase + nj*16 + l15] = acc[mi][nj][j] + bb[nj];
        }
    }
  }
}

// ---------------- both BN finalizes ----------------
__global__ void k_bn_finalize2(const float* __restrict__ sf, const float* __restrict__ gf,
                               const float* __restrict__ bef, float* __restrict__ pf,
                               const float* __restrict__ sg, const float* __restrict__ gg,
                               const float* __restrict__ beg, float* __restrict__ pg){
  int c = blockIdx.x*blockDim.x + threadIdx.x;
  if (c < 512){
    float mean = sf[c]*(1.f/(float)MFINE);
    float var  = sf[512+c]*(1.f/(float)MFINE) - mean*mean;
    float sc = gf[c]*rsqrtf(var + 1e-5f);
    pf[c] = sc; pf[512+c] = bef[c] - mean*sc;
  } else if (c < 1280){
    int d = c - 512;
    float mean = sg[d]*(1.f/(float)B_SZ);
    float var  = sg[768+d]*(1.f/(float)B_SZ) - mean*mean;
    float sc = gg[d]*rsqrtf(var + 1e-5f);
    pg[d] = sc; pg[768+d] = beg[d] - mean*sc;
  }
}

// ---------------- mean over tokens of BN(h) -> bf16 [256,512] ----------------
__global__ __launch_bounds__(256)
void k_hmean(const ushort* __restrict__ h, const float* __restrict__ par,
             ushort* __restrict__ hm){
  __shared__ float red[4][512];
  int b = blockIdx.x;
  int lane = threadIdx.x & 63, w = threadIdx.x >> 6;
  int c0 = lane*8;
  float4 sca = *(const float4*)&par[c0],     scb = *(const float4*)&par[c0+4];
  float4 sha = *(const float4*)&par[512+c0], shb = *(const float4*)&par[512+c0+4];
  float a0=0,a1=0,a2=0,a3=0,a4=0,a5=0,a6=0,a7=0;
  const ushort* base = h + (size_t)b*NTOK*DLOC;
  for (int n=w; n<NTOK; n+=4){
    us8 v = *(const us8*)&base[(size_t)n*DLOC + c0];
    a0 += fmaxf(bf2f(v[0])*sca.x+sha.x, 0.f);
    a1 += fmaxf(bf2f(v[1])*sca.y+sha.y, 0.f);
    a2 += fmaxf(bf2f(v[2])*sca.z+sha.z, 0.f);
    a3 += fmaxf(bf2f(v[3])*sca.w+sha.w, 0.f);
    a4 += fmaxf(bf2f(v[4])*scb.x+shb.x, 0.f);
    a5 += fmaxf(bf2f(v[5])*scb.y+shb.y, 0.f);
    a6 += fmaxf(bf2f(v[6])*scb.z+shb.z, 0.f);
    a7 += fmaxf(bf2f(v[7])*scb.w+shb.w, 0.f);
  }
  red[w][c0+0]=a0; red[w][c0+1]=a1; red[w][c0+2]=a2; red[w][c0+3]=a3;
  red[w][c0+4]=a4; red[w][c0+5]=a5; red[w][c0+6]=a6; red[w][c0+7]=a7;
  __syncthreads();
  int c = threadIdx.x;
  float s = red[0][c]+red[1][c]+red[2][c]+red[3][c];
  hm[(size_t)b*DLOC + c] = f2bf(s*(1.f/197.f));
  c += 256;
  s = red[0][c]+red[1][c]+red[2][c]+red[3][c];
  hm[(size_t)b*DLOC + c] = f2bf(s*(1.f/197.f));
}

// ---------------- weight converts + stats zero, one launch ----------------
__global__ void k_wconv(const float* __restrict__ w0,const float* __restrict__ w1,
                        const float* __restrict__ w2,const float* __restrict__ w3,
                        ushort* __restrict__ o0, ushort* __restrict__ o1,
                        ushort* __restrict__ o2, ushort* __restrict__ o3,
                        float* __restrict__ stats){
  int i = blockIdx.x*blockDim.x + threadIdx.x;
  if (i < 640){ float4 z = {0.f,0.f,0.f,0.f}; ((float4*)stats)[i] = z; }
  if (i < 188416){
    const float* src; ushort* dst; int k;
    if (i < 32768){ src=w0; dst=o0; k=i; }
    else if (i < 65536){ src=w1; dst=o1; k=i-32768; }
    else if (i < 114688){ src=w2; dst=o2; k=i-65536; }
    else { src=w3; dst=o3; k=i-114688; }
    float4 a = ((const float4*)src)[k*2];
    float4 b = ((const float4*)src)[k*2+1];
    us8 o;
    o[0]=f2bf(a.x); o[1]=f2bf(a.y); o[2]=f2bf(a.z); o[3]=f2bf(a.w);
    o[4]=f2bf(b.x); o[5]=f2bf(b.y); o[6]=f2bf(b.z); o[7]=f2bf(b.w);
    ((us8*)dst)[k] = o;
  }
}

// ---------------- row L2 normalize + logit_scale exp ----------------
__global__ __launch_bounds__(256)
void k_l2norm(const float* __restrict__ gbuf, float* __restrict__ outg,
              const float* __restrict__ ls, float* __restrict__ lse){
  int b = blockIdx.x, t = threadIdx.x;
  if (b==0 && t==0) lse[0] = expf(ls[0]);
  float v0 = gbuf[(size_t)b*DGLB + t];
  float v1 = gbuf[(size_t)b*DGLB + 256 + t];
  float v2 = gbuf[(size_t)b*DGLB + 512 + t];
  float s = v0*v0 + v1*v1 + v2*v2;
  s += __shfl_xor(s, 1);  s += __shfl_xor(s, 2);  s += __shfl_xor(s, 4);
  s += __shfl_xor(s, 8);  s += __shfl_xor(s, 16); s += __shfl_xor(s, 32);
  __shared__ float red[4];
  if ((t&63)==0) red[t>>6] = s;
  __syncthreads();
  float r = rsqrtf(red[0]+red[1]+red[2]+red[3]);
  outg[(size_t)b*DGLB + t]       = v0*r;
  outg[(size_t)b*DGLB + 256 + t] = v1*r;
  outg[(size_t)b*DGLB + 512 + t] = v2*r;
}

// ---------------- top-k (wave 0) + whole-block gather ----------------
__global__ __launch_bounds__(256)
void k_topk_gather(const float* __restrict__ attn, const float* __restrict__ X,
                   float* __restrict__ T){
  __shared__ int sel_s[6];
  int b = blockIdx.x, tid = threadIdx.x, lane = tid & 63;
  if (tid < 64){
    const float* a = attn + (size_t)b*(NTOK-1);
    float v[4];
    v[0]=a[lane]; v[1]=a[lane+64]; v[2]=a[lane+128];
    v[3] = (lane<4) ? a[lane+192] : -3.4e38f;
    if (lane==0) sel_s[0] = 0;
    #pragma unroll
    for (int rr=0; rr<TOPK; rr++){
      float bv = v[0]; int bi = lane;
      if (v[1]>bv){bv=v[1]; bi=lane+64;}
      if (v[2]>bv){bv=v[2]; bi=lane+128;}
      if (v[3]>bv){bv=v[3]; bi=lane+192;}
      #pragma unroll
      for (int s=1;s<64;s<<=1){
        float ov = __shfl_xor(bv, s);
        int oi = __shfl_xor(bi, s);
        if (ov>bv || (ov==bv && oi<bi)){ bv=ov; bi=oi; }
      }
      if (lane==0) sel_s[rr+1] = bi+1;
      if ((bi&63)==lane && (bi>>6) < 4) v[bi>>6] = -3.4e38f;
    }
  }
  __syncthreads();
  // copy 6 rows x 512 floats = 768 float4
  for (int idx = tid; idx < 768; idx += 256){
    int j = idx >> 7, c = (idx & 127);
    const float4* s = (const float4*)(X + ((size_t)b*NTOK + sel_s[j])*DLOC) + c;
    float4* d = (float4*)(T + ((size_t)b*7 + j)*DLOC) + c;
    *d = *s;
  }
}

// ---------------- launch ----------------
extern "C" void kernel_launch(void* const* d_in, const int* in_sizes, int n_in,
                              void* d_out, int out_size, void* d_ws, size_t ws_size,
                              hipStream_t stream){
  const float* image_features = (const float*)d_in[0];
  const float* fine_feat      = (const float*)d_in[1];
  const float* fine_attn      = (const float*)d_in[2];
  const float* logit_scale    = (const float*)d_in[3];
  const float* vpt_w1  = (const float*)d_in[4];
  const float* vpt_b1  = (const float*)d_in[5];
  const float* vpt_g1  = (const float*)d_in[6];
  const float* vpt_be1 = (const float*)d_in[7];
  const float* vpt_w2  = (const float*)d_in[8];
  const float* vpt_b2  = (const float*)d_in[9];
  const float* mid_w1  = (const float*)d_in[10];
  const float* mid_b1  = (const float*)d_in[11];
  const float* mid_g1  = (const float*)d_in[12];
  const float* mid_be1 = (const float*)d_in[13];
  const float* mid_w2  = (const float*)d_in[14];
  const float* mid_b2  = (const float*)d_in[15];

  float* out = (float*)d_out;
  char* ws = (char*)d_ws;
  size_t off = 0;
  auto alloc = [&](size_t bytes)->void*{
    void* p = ws + off; off += (bytes + 255) & ~(size_t)255; return p;
  };
  ushort* h_bf   = (ushort*)alloc((size_t)MFINE*DLOC*2);
  ushort* wm1    = (ushort*)alloc(512*512*2);
  ushort* wm2    = (ushort*)alloc(512*512*2);
  ushort* wv1    = (ushort*)alloc(768*512*2);
  ushort* wv2    = (ushort*)alloc((size_t)768*768*2);
  ushort* h1g    = (ushort*)alloc(256*768*2);
  ushort* hnmean = (ushort*)alloc(256*512*2);
  float*  gbuf   = (float*)alloc(256*768*4);
  float*  stats  = (float*)alloc(2560*4);
  float*  par_f  = (float*)alloc(512*2*4);
  float*  par_g  = (float*)alloc(768*2*4);
  float*  stats_f = stats;
  float*  stats_g = stats + 1024;

  // weights -> bf16 + zero stats
  k_wconv<<<736,256,0,stream>>>(mid_w1, mid_w2, vpt_w1, vpt_w2, wm1, wm2, wv1, wv2, stats);

  // GEMM1 (fine + global merged): h = bf16(A_f32) @ W1^T + b1, channel stats
  {
    int nblk0 = (MFINE/BM)*(DLOC/BN);     // 1576
    int nblk1 = (B_SZ/BM)*(DGLB/BN);      // 12
    k_gemm2ph<1,0><<<nblk0+nblk1,256,0,stream>>>(
      fine_feat, nullptr, wm1, mid_b1, nullptr, h_bf, nullptr, nullptr, stats_f,
      DLOC, DLOC, DLOC/BN, MFINE, nblk0,
      image_features, wv1, vpt_b1, nullptr, h1g, nullptr, stats_g,
      DGLB, DLOC, DGLB/BN);
  }

  // BN finalize (both)
  k_bn_finalize2<<<5,256,0,stream>>>(stats_f, mid_g1, mid_be1, par_f,
                                     stats_g, vpt_g1, vpt_be1, par_g);

  // token-mean of BN(h) for the avg rows
  k_hmean<<<B_SZ,256,0,stream>>>(h_bf, par_f, hnmean);

  // GEMM2 (fine+ext + global merged): BN+ReLU fused on A
  float* Xout = out + OUT_FINE;
  float* Tout = out + OUT_TOP;
  {
    int nblk0 = ((MFINE+256)/BM)*(DLOC/BN);  // 1584
    int nblk1 = (B_SZ/BM)*(DGLB/BN);         // 12
    k_gemm2ph<2,1><<<nblk0+nblk1,256,0,stream>>>(
      h_bf, hnmean, wm2, mid_b2, par_f, nullptr, Xout, Tout, nullptr,
      DLOC, DLOC, DLOC/BN, MFINE, nblk0,
      h1g, wv2, vpt_b2, par_g, nullptr, gbuf, nullptr,
      DGLB, DGLB, DGLB/BN);
  }

  // epilogues
  k_l2norm<<<B_SZ,256,0,stream>>>(gbuf, out + OUT_GFEAT, logit_scale, out + OUT_LSE);
  k_topk_gather<<<B_SZ,256,0,stream>>>(fine_attn, Xout, Tout);
}